// Round 15
// baseline (209.399 us; speedup 1.0000x reference)
//
#include <hip/hip_runtime.h>
#include <math.h>

#define EMBED    256
#define HIDDEN   512
#define Nn       2000
#define Ee       2000
#define BMT      64      // edges per tile
#define TILES    16      // tiles per persistent block (1024 edges)
#define NBLK     250     // 250 * 1024 = 256000 edges
#define NTHREADS 512     // waves 0-3 consumers (MFMA), 4-7 producers (stage)
#define NCHUNK   (TILES * 8)   // 128 chunks of 64-k
#define FP       72      // shorts per feat row (64 + 8 pad; measured 0-conflict)

typedef __attribute__((ext_vector_type(8)))  short bf16x8;
typedef __attribute__((ext_vector_type(16))) float f32x16;

static __device__ __forceinline__ short f2bf(float f) {
  unsigned u = __builtin_bit_cast(unsigned, f);
  u += 0x7fffu + ((u >> 16) & 1u);
  return (short)(u >> 16);
}

static __device__ __forceinline__ bf16x8 cvt8(float4 a, float4 b) {
  bf16x8 v;
  v[0]=f2bf(a.x); v[1]=f2bf(a.y); v[2]=f2bf(a.z); v[3]=f2bf(a.w);
  v[4]=f2bf(b.x); v[5]=f2bf(b.y); v[6]=f2bf(b.z); v[7]=f2bf(b.w);
  return v;
}

#define LBAR() do { asm volatile("s_waitcnt lgkmcnt(0)" ::: "memory"); \
                    __builtin_amdgcn_s_barrier(); \
                    asm volatile("" ::: "memory"); } while (0)

// ---- prep: W1 (513x512 f32 [k][n]) -> fragment-major W1F bf16 ----
// W1F[((tn*32 + tk)*64 + lane)*8 + q] = W1[tk*16 + (lane>>5)*8 + q][tn*32 + (lane&31)]
__global__ void w1f_kernel(const float* __restrict__ W1, short* __restrict__ W1F) {
  const int t  = blockIdx.x * 512 + threadIdx.x;   // 32768 fragment-lanes
  const int l  = t & 63;
  const int tk = (t >> 6) & 31;
  const int tn = t >> 11;
  const int n  = tn * 32 + (l & 31);
  const int k0 = tk * 16 + (l >> 5) * 8;
  bf16x8 v;
#pragma unroll
  for (int q = 0; q < 8; ++q)
    v[q] = f2bf(W1[(size_t)(k0 + q) * HIDDEN + n]);
  *(bf16x8*)(W1F + (size_t)t * 8) = v;
}

// ---- main: producer/consumer waves, triple-buffered 64-k feat chunks ----
__global__ __launch_bounds__(NTHREADS, 2)
void edge_kernel(const float* __restrict__ emb, const float* __restrict__ locs,
                 const int* __restrict__ edges, const int* __restrict__ dbias,
                 const float* __restrict__ W1, const float* __restrict__ b1,
                 const float* __restrict__ W2, const float* __restrict__ b2,
                 const short* __restrict__ W1F, float* __restrict__ out)
{
  __shared__ short feat[3][BMT][FP];      // 27,648 B (3-buf 64-k chunks)
  __shared__ float b1_s[HIDDEN], w513_s[HIDDEN], w2_s[HIDDEN];  // 6 KB
  __shared__ float part_s[2][4][BMT];     // 2 KB [parity][consumer][edge]
  __shared__ float dist_s[2][BMT];
  __shared__ int   valid_s[2][BMT];
  __shared__ int   ibase_s[2][BMT], jbase_s[2][BMT];   // total ~38 KB

  const int tid = threadIdx.x;

  // bijective XCD-chunked swizzle over 250 blocks (xcd 0,1 -> 32; 2..7 -> 31)
  const int orig = blockIdx.x;
  const int xcd  = orig & 7;
  const int idx  = orig >> 3;
  const int sbid = (xcd < 2 ? xcd * 32 : 64 + (xcd - 2) * 31) + idx;
  const int eblk = sbid * (TILES * BMT);

  b1_s[tid]   = b1[tid];
  w513_s[tid] = W1[(size_t)512 * HIDDEN + tid];
  w2_s[tid]   = W2[tid];
  const float b2s_base = b2[0] + (float)dbias[0];

  const int lane = tid & 63;
  const int w    = tid >> 6;      // wave 0..7
  const int ln31 = lane & 31;
  const int kg   = lane >> 5;

  // producer-local ids (waves 4-7)
  const int pt = tid - 256;       // 0..255
  const int e  = pt >> 2;         // edge 0..63
  const int sq = pt & 3;          // 16-float quarter of the 64-k row

  auto do_meta = [&](int T) {     // producers, pt < BMT
    const int g  = eblk + T * BMT + pt;
    const int b  = g / Ee;
    const int i0 = edges[2 * g];
    const int j0 = edges[2 * g + 1];
    valid_s[T & 1][pt] = (i0 >= 0) && (j0 >= 0);
    const int ib = b * Nn + (i0 < 0 ? 0 : i0);
    const int jb = b * Nn + (j0 < 0 ? 0 : j0);
    ibase_s[T & 1][pt] = ib;
    jbase_s[T & 1][pt] = jb;
    const float dx = locs[2 * (size_t)ib]     - locs[2 * (size_t)jb];
    const float dy = locs[2 * (size_t)ib + 1] - locs[2 * (size_t)jb + 1];
    dist_s[T & 1][pt] = sqrtf(dx * dx + dy * dy);
  };

  // stage global chunk gc into feat[buf] (producers, 256 threads)
  auto stage = [&](int gc, int buf) {
    const int T    = gc >> 3;
    const int ph   = gc & 7;
    const int side = ph >> 2;     // 0 = emb_i, 1 = emb_j
    const int q    = ph & 3;      // 64-k quarter
    const int rb = side ? jbase_s[T & 1][e] : ibase_s[T & 1][e];
    const float* src = emb + (size_t)rb * EMBED + q * 64 + sq * 16;
    float4 g0 = *(const float4*)(src);
    float4 g1 = *(const float4*)(src + 4);
    float4 g2 = *(const float4*)(src + 8);
    float4 g3 = *(const float4*)(src + 12);
    *(bf16x8*)&feat[buf][e][sq * 16]     = cvt8(g0, g1);
    *(bf16x8*)&feat[buf][e][sq * 16 + 8] = cvt8(g2, g3);
  };

  // ---- prologue ----
  if (w >= 4 && pt < BMT) do_meta(0);
  LBAR();
  if (w >= 4) { stage(0, 0); stage(1, 1); }
  LBAR();

  f32x16 acc[2][4];               // consumers: [et 0..1][nt 0..3]
#pragma unroll
  for (int et = 0; et < 2; ++et)
#pragma unroll
    for (int nt = 0; nt < 4; ++nt)
#pragma unroll
      for (int q = 0; q < 16; ++q) acc[et][nt][q] = 0.f;

  // consumer wave w owns n-slice [w*128, +128): wa frag F = (w*4+nt)*32 + tk
  const short* wfb = W1F + (size_t)(w * 4 * 32) * 512 + lane * 8;

#pragma unroll 1
  for (int p = 0; p < NCHUNK; ++p) {
    const int buf = p % 3;

    if (w < 4) {
      // ---------------- consumer: wa reg-dbuf + fb LDS + MFMA ----------------
      const int tk0 = (p & 7) * 4;    // PER-TILE 16-k index (R14 bug: was p*4)
      bf16x8 wc[4], wn[4];
#pragma unroll
      for (int nt = 0; nt < 4; ++nt)
        wc[nt] = *(const bf16x8*)(wfb + (size_t)(nt * 32 + tk0) * 512);
#pragma unroll
      for (int ks = 0; ks < 4; ++ks) {
        if (ks < 3) {
#pragma unroll
          for (int nt = 0; nt < 4; ++nt)
            wn[nt] = *(const bf16x8*)(wfb + (size_t)(nt * 32 + tk0 + ks + 1) * 512);
        }
        bf16x8 fb0 = *(const bf16x8*)(&feat[buf][ln31][ks * 16 + kg * 8]);
        bf16x8 fb1 = *(const bf16x8*)(&feat[buf][32 + ln31][ks * 16 + kg * 8]);
        __builtin_amdgcn_s_setprio(1);
#pragma unroll
        for (int nt = 0; nt < 4; ++nt) {
          acc[0][nt] = __builtin_amdgcn_mfma_f32_32x32x16_bf16(wc[nt], fb0, acc[0][nt], 0, 0, 0);
          acc[1][nt] = __builtin_amdgcn_mfma_f32_32x32x16_bf16(wc[nt], fb1, acc[1][nt], 0, 0, 0);
        }
        __builtin_amdgcn_s_setprio(0);
#pragma unroll
        for (int nt = 0; nt < 4; ++nt) wc[nt] = wn[nt];
      }

      if ((p & 7) == 7) {
        // ---- tile epilogue: dist col + bias + relu + in-lane W2 dot ----
        const int T   = p >> 3;
        const int par = T & 1;
        float dv[2], ps[2];
#pragma unroll
        for (int et = 0; et < 2; ++et) {
          dv[et] = dist_s[par][et * 32 + ln31];
          ps[et] = 0.f;
        }
#pragma unroll
        for (int nt = 0; nt < 4; ++nt) {
#pragma unroll
          for (int r = 0; r < 16; ++r) {
            const int n = w * 128 + nt * 32 + (r & 3) + ((r >> 2) << 3) + (kg << 2);
            const float bias = b1_s[n];
            const float wd   = w513_s[n];
            const float w2v  = w2_s[n];
#pragma unroll
            for (int et = 0; et < 2; ++et) {
              float pv = acc[et][nt][r] + bias + dv[et] * wd;
              ps[et] += fmaxf(pv, 0.f) * w2v;
            }
          }
        }
#pragma unroll
        for (int et = 0; et < 2; ++et) ps[et] += __shfl_xor(ps[et], 32, 64);
        if (lane < 32) {
#pragma unroll
          for (int et = 0; et < 2; ++et) part_s[par][w][et * 32 + ln31] = ps[et];
        }
#pragma unroll
        for (int et = 0; et < 2; ++et)
#pragma unroll
          for (int nt = 0; nt < 4; ++nt)
#pragma unroll
            for (int q = 0; q < 16; ++q) acc[et][nt][q] = 0.f;
      }
    } else {
      // ---------------- producer: all HBM traffic + stores ------------------
      // meta one phase before first staging use: when (p+3) hits a tile start
      if (((p + 3) & 7) == 0) {
        const int T = (p + 3) >> 3;
        if (T < TILES && pt < BMT) do_meta(T);
      }
      // stage chunk p+2 into buf (p+2)%3
      if (p + 2 < NCHUNK) stage(p + 2, (p + 2) % 3);
      // store logits of tile (p>>3)-1 at each tile boundary
      if ((p & 7) == 0 && p > 0 && pt < BMT) {
        const int S   = (p >> 3) - 1;
        const int par = S & 1;
        float s = part_s[par][0][pt] + part_s[par][1][pt] +
                  part_s[par][2][pt] + part_s[par][3][pt] + b2s_base;
        if (!valid_s[par][pt]) s = -__builtin_inff();
        out[eblk + S * BMT + pt] = s;
      }
    }
    LBAR();
  }

  // final store: tile TILES-1 (parity 1)
  if (w >= 4 && pt < BMT) {
    float s = part_s[1][0][pt] + part_s[1][1][pt] +
              part_s[1][2][pt] + part_s[1][3][pt] + b2s_base;
    if (!valid_s[1][pt]) s = -__builtin_inff();
    out[eblk + (TILES - 1) * BMT + pt] = s;
  }
}

extern "C" void kernel_launch(void* const* d_in, const int* in_sizes, int n_in,
                              void* d_out, int out_size, void* d_ws, size_t ws_size,
                              hipStream_t stream) {
  const float* emb   = (const float*)d_in[0];
  const float* locs  = (const float*)d_in[1];
  const int*   edges = (const int*)d_in[2];
  const int*   dbias = (const int*)d_in[3];
  const float* W1    = (const float*)d_in[4];
  const float* b1    = (const float*)d_in[5];
  const float* W2    = (const float*)d_in[6];
  const float* b2    = (const float*)d_in[7];
  float*       out   = (float*)d_out;
  short*       W1F   = (short*)d_ws;   // 512*512*2 = 512 KiB fragment-major

  w1f_kernel<<<dim3(64), dim3(512), 0, stream>>>(W1, W1F);
  edge_kernel<<<dim3(NBLK), dim3(NTHREADS), 0, stream>>>(
      emb, locs, edges, dbias, W1, b1, W2, b2, (const short*)W1F, out);
}